// Round 2
// baseline (392.493 us; speedup 1.0000x reference)
//
#include <hip/hip_runtime.h>

// Problem dims: T=256, B=128, I=512, H=512
#define T_STEPS 256
#define B_DIM   128
#define I_DIM   512
#define H_DIM   512
#define M_DIM   (T_STEPS * B_DIM)   // 32768

// GEMM tiling
#define BM 128
#define BN 128
#define BK 32
#define LDK 36   // BK + 4: keeps rows 16B-aligned AND de-aliases row-start banks
                 // (row*36 mod 32 = 4*row -> distinct banks for strided frag rows)

// h[m][n] = sum_k x[m][k] * W[n][k] + b[n]
// A (x): [M][K] row-major; Bw (W): [N][K] row-major. Both K-contiguous.
// LDS layout [row][k] (natural): staging stores are contiguous b128 runs
// (conflict-free); fragment reads are b128 along k with strided row mapping
// (m = ty + 16*i) so concurrent lanes hit distinct bank groups.
__global__ __launch_bounds__(256) void gemm_bias_f32(
    const float* __restrict__ A,
    const float* __restrict__ Bw,
    const float* __restrict__ bias,
    float* __restrict__ C)
{
    __shared__ float As[BM][LDK];   // [m][k]
    __shared__ float Bs[BN][LDK];   // [n][k]

    const int tid = threadIdx.x;
    const int tx  = tid & 15;   // n direction
    const int ty  = tid >> 4;   // m direction
    const int m0  = blockIdx.y * BM;
    const int n0  = blockIdx.x * BN;

    float acc[8][8];
    #pragma unroll
    for (int i = 0; i < 8; i++)
        #pragma unroll
        for (int j = 0; j < 8; j++)
            acc[i][j] = 0.0f;

    // Staging: each thread loads 4 float4 from A and Bw (k-contiguous).
    const int lrow = tid >> 3;        // 0..31
    const int lk   = (tid & 7) * 4;   // 0,4,...,28

    const float* Aptr = A  + (size_t)(m0 + lrow) * I_DIM + lk;
    const float* Bptr = Bw + (size_t)(n0 + lrow) * I_DIM + lk;

    for (int k0 = 0; k0 < I_DIM; k0 += BK) {
        float4 av[4], bv[4];
        #pragma unroll
        for (int p = 0; p < 4; p++) {
            av[p] = *(const float4*)(Aptr + (size_t)(p * 32) * I_DIM + k0);
            bv[p] = *(const float4*)(Bptr + (size_t)(p * 32) * I_DIM + k0);
        }

        __syncthreads();   // protect previous iteration's LDS reads

        #pragma unroll
        for (int p = 0; p < 4; p++) {
            *(float4*)&As[lrow + 32 * p][lk] = av[p];   // contiguous b128 run per 8 lanes
            *(float4*)&Bs[lrow + 32 * p][lk] = bv[p];
        }

        __syncthreads();

        #pragma unroll
        for (int k = 0; k < BK; k += 4) {
            float4 af[8], bf[8];
            #pragma unroll
            for (int i = 0; i < 8; i++)
                af[i] = *(const float4*)&As[ty + 16 * i][k];
            #pragma unroll
            for (int j = 0; j < 8; j++)
                bf[j] = *(const float4*)&Bs[tx + 16 * j][k];

            #pragma unroll
            for (int i = 0; i < 8; i++)
                #pragma unroll
                for (int j = 0; j < 8; j++) {
                    acc[i][j] = fmaf(af[i].x, bf[j].x, acc[i][j]);
                    acc[i][j] = fmaf(af[i].y, bf[j].y, acc[i][j]);
                    acc[i][j] = fmaf(af[i].z, bf[j].z, acc[i][j]);
                    acc[i][j] = fmaf(af[i].w, bf[j].w, acc[i][j]);
                }
        }
    }

    // Epilogue: bias + scalar stores (rows strided 16; lanes tx consecutive -> 64B runs)
    float bcol[8];
    #pragma unroll
    for (int j = 0; j < 8; j++)
        bcol[j] = bias[n0 + tx + 16 * j];

    #pragma unroll
    for (int i = 0; i < 8; i++) {
        const int m = m0 + ty + 16 * i;
        float* cp = C + (size_t)m * H_DIM + n0 + tx;
        #pragma unroll
        for (int j = 0; j < 8; j++)
            cp[16 * j] = acc[i][j] + bcol[j];
    }
}

// LIF scan over T: v <- 0.5*v + h_t ; s = (v >= 1) ; v <- s ? 0 : v
// Software-pipelined: chunk c+1's loads stay in flight during compute/store
// of chunk c (two static register buffers -> no scratch spills).
#define U 16
#define NC (T_STEPS / U)   // 16 chunks
__global__ __launch_bounds__(256) void lif_scan(
    const float* __restrict__ h,
    float* __restrict__ out)
{
    const int n   = B_DIM * H_DIM;   // 65536
    const int idx = blockIdx.x * 256 + threadIdx.x;
    const float* hp = h + idx;
    float* op = out + idx;

    float va[U], vb[U];
    #pragma unroll
    for (int i = 0; i < U; i++)
        va[i] = hp[(size_t)i * n];

    float v = 0.0f;
    for (int c = 0; c < NC; c += 2) {
        // prefetch chunk c+1 into vb
        if (c + 1 < NC) {
            #pragma unroll
            for (int i = 0; i < U; i++)
                vb[i] = hp[(size_t)((c + 1) * U + i) * n];
        }
        // compute chunk c from va
        #pragma unroll
        for (int i = 0; i < U; i++) {
            v = 0.5f * v + va[i];
            const bool fire = (v >= 1.0f);
            __builtin_nontemporal_store(fire ? 1.0f : 0.0f,
                                        &op[(size_t)(c * U + i) * n]);
            v = fire ? 0.0f : v;
        }
        // prefetch chunk c+2 into va
        if (c + 2 < NC) {
            #pragma unroll
            for (int i = 0; i < U; i++)
                va[i] = hp[(size_t)((c + 2) * U + i) * n];
        }
        // compute chunk c+1 from vb
        #pragma unroll
        for (int i = 0; i < U; i++) {
            v = 0.5f * v + vb[i];
            const bool fire = (v >= 1.0f);
            __builtin_nontemporal_store(fire ? 1.0f : 0.0f,
                                        &op[(size_t)((c + 1) * U + i) * n]);
            v = fire ? 0.0f : v;
        }
    }
}

extern "C" void kernel_launch(void* const* d_in, const int* in_sizes, int n_in,
                              void* d_out, int out_size, void* d_ws, size_t ws_size,
                              hipStream_t stream) {
    const float* x = (const float*)d_in[0];   // (T, B, I) fp32
    const float* W = (const float*)d_in[1];   // (H, I)    fp32
    const float* b = (const float*)d_in[2];   // (H,)      fp32
    float* out = (float*)d_out;               // (T, B, H) fp32 spikes
    float* h   = (float*)d_ws;                // (T*B, H)  fp32 scratch, 64 MB

    dim3 grid(H_DIM / BN, M_DIM / BM);        // (4, 256)
    gemm_bias_f32<<<grid, 256, 0, stream>>>(x, W, b, h);

    lif_scan<<<(B_DIM * H_DIM) / 256, 256, 0, stream>>>(h, out);
}

// Round 3
// 312.396 us; speedup vs baseline: 1.2564x; 1.2564x over previous
//
#include <hip/hip_runtime.h>

// Problem dims: T=256, B=128, I=512, H=512
#define T_STEPS 256
#define B_DIM   128
#define I_DIM   512
#define H_DIM   512
#define M_DIM   (T_STEPS * B_DIM)   // 32768

// GEMM tiling
#define BM 128
#define BN 128
#define BK 32
#define LDR 148   // floats per k-row. 148 % 8 == 4 -> consecutive k-rows land in
                  // opposite bank halves (16(q&1) term); capacity >= 144 needed
                  // for swizzled columns; 16B-aligned rows.

typedef float v2f __attribute__((ext_vector_type(2)));

// LDS placement: element (k, col) lives at [k*LDR + P(k,col)] with
//   P(k,col) = (col + 4*(col>>5)) ^ (4*((k>>3)&3))
// - +4 pad every 32 cols: B-frag reads (16 unique addrs, starts 8tx mod 32)
//   spread from 4-way to 2-way
// - XOR by (k>>3): a thread's 4-consecutive-k scalar stores at fixed col
//   spread from 4/8-way to 2-way
// 2-way is free on gfx950 (m136). Verified by bank enumeration.

__global__ __launch_bounds__(256, 2) void gemm_bias_f32(
    const float* __restrict__ A,
    const float* __restrict__ Bw,
    const float* __restrict__ bias,
    float* __restrict__ C)
{
    __shared__ float As[BK * LDR];
    __shared__ float Bs[BK * LDR];

    const int tid = threadIdx.x;
    const int tx  = tid & 15;   // n direction
    const int ty  = tid >> 4;   // m direction
    const int m0  = blockIdx.y * BM;
    const int n0  = blockIdx.x * BN;

    v2f acc[8][4];
    #pragma unroll
    for (int i = 0; i < 8; i++)
        #pragma unroll
        for (int j = 0; j < 4; j++)
            acc[i][j] = (v2f){0.0f, 0.0f};

    // Staging mapping: thread loads 4x float4 (k-contiguous) from A and Bw.
    const int lrow = tid >> 3;        // 0..31
    const int lk   = (tid & 7) * 4;   // 0,4,...,28
    const int s_t  = 4 * ((lk >> 3) & 3);   // store-side XOR, per-thread const

    // Read-side swizzled column bases (loc(col) = col + 4*(col>>5))
    const int tyloc = 8 * ty + 4 * (ty >> 2);
    const int txloc = 8 * tx + 4 * (tx >> 2);

    const float* Aptr = A  + (size_t)(m0 + lrow) * I_DIM + lk;
    const float* Bptr = Bw + (size_t)(n0 + lrow) * I_DIM + lk;

    float4 av[4], bv[4];
    #pragma unroll
    for (int p = 0; p < 4; p++) {
        av[p] = *(const float4*)(Aptr + (size_t)(p * 32) * I_DIM);
        bv[p] = *(const float4*)(Bptr + (size_t)(p * 32) * I_DIM);
    }

    for (int k0 = 0; k0 < I_DIM; k0 += BK) {
        __syncthreads();   // previous iteration's LDS reads done

        #pragma unroll
        for (int p = 0; p < 4; p++) {
            const int col = (lrow + 36 * p) ^ s_t;   // loc(lrow+32p) ^ s_t
            float* a = &As[lk * LDR + col];
            a[0 * LDR] = av[p].x;
            a[1 * LDR] = av[p].y;
            a[2 * LDR] = av[p].z;
            a[3 * LDR] = av[p].w;
            float* b = &Bs[lk * LDR + col];
            b[0 * LDR] = bv[p].x;
            b[1 * LDR] = bv[p].y;
            b[2 * LDR] = bv[p].z;
            b[3 * LDR] = bv[p].w;
        }

        __syncthreads();

        // Prefetch next tile into registers; loads stay in flight across compute.
        if (k0 + BK < I_DIM) {
            #pragma unroll
            for (int p = 0; p < 4; p++) {
                av[p] = *(const float4*)(Aptr + (size_t)(p * 32) * I_DIM + k0 + BK);
                bv[p] = *(const float4*)(Bptr + (size_t)(p * 32) * I_DIM + k0 + BK);
            }
        }

        #pragma unroll
        for (int k = 0; k < BK; k++) {
            const int s = 4 * ((k >> 3) & 3);   // compile-time per unrolled k
            const float4 a0 = *(const float4*)&As[k * LDR + ((tyloc)     ^ s)];
            const float4 a1 = *(const float4*)&As[k * LDR + ((tyloc + 4) ^ s)];
            const float4 b0 = *(const float4*)&Bs[k * LDR + ((txloc)     ^ s)];
            const float4 b1 = *(const float4*)&Bs[k * LDR + ((txloc + 4) ^ s)];

            const v2f bb0 = (v2f){b0.x, b0.y};
            const v2f bb1 = (v2f){b0.z, b0.w};
            const v2f bb2 = (v2f){b1.x, b1.y};
            const v2f bb3 = (v2f){b1.z, b1.w};
            const float aa[8] = {a0.x, a0.y, a0.z, a0.w, a1.x, a1.y, a1.z, a1.w};

            #pragma unroll
            for (int i = 0; i < 8; i++) {
                const v2f as = (v2f){aa[i], aa[i]};
                acc[i][0] = __builtin_elementwise_fma(as, bb0, acc[i][0]);
                acc[i][1] = __builtin_elementwise_fma(as, bb1, acc[i][1]);
                acc[i][2] = __builtin_elementwise_fma(as, bb2, acc[i][2]);
                acc[i][3] = __builtin_elementwise_fma(as, bb3, acc[i][3]);
            }
        }
    }

    // Epilogue: bias + float4 stores (round-1 pattern: full-line coalescing)
    float bcol[8];
    #pragma unroll
    for (int j = 0; j < 8; j++)
        bcol[j] = bias[n0 + tx * 8 + j];

    #pragma unroll
    for (int i = 0; i < 8; i++) {
        const int m = m0 + ty * 8 + i;
        float4 o0, o1;
        o0.x = acc[i][0].x + bcol[0];
        o0.y = acc[i][0].y + bcol[1];
        o0.z = acc[i][1].x + bcol[2];
        o0.w = acc[i][1].y + bcol[3];
        o1.x = acc[i][2].x + bcol[4];
        o1.y = acc[i][2].y + bcol[5];
        o1.z = acc[i][3].x + bcol[6];
        o1.w = acc[i][3].y + bcol[7];
        float* cp = C + (size_t)m * H_DIM + n0 + tx * 8;
        *(float4*)(cp)     = o0;
        *(float4*)(cp + 4) = o1;
    }
}

// LIF scan over T: v <- 0.5*v + h_t ; s = (v >= 1) ; v <- s ? 0 : v
// One thread per neuron; double-buffered 32-deep prefetch keeps ~8 KB/wave of
// global loads in flight (>= BW*latency need at 4 waves/CU).
#define U  32
#define NC (T_STEPS / U)   // 8 chunks
__global__ __launch_bounds__(256) void lif_scan(
    const float* __restrict__ h,
    float* __restrict__ out)
{
    const int n   = B_DIM * H_DIM;   // 65536
    const int idx = blockIdx.x * 256 + threadIdx.x;
    const float* hp = h + idx;
    float* op = out + idx;

    float va[U], vb[U];
    #pragma unroll
    for (int i = 0; i < U; i++)
        va[i] = hp[(size_t)i * n];

    float v = 0.0f;
    #pragma unroll
    for (int c = 0; c < NC; c += 2) {
        // prefetch chunk c+1
        #pragma unroll
        for (int i = 0; i < U; i++)
            vb[i] = hp[(size_t)((c + 1) * U + i) * n];
        // compute chunk c
        #pragma unroll
        for (int i = 0; i < U; i++) {
            v = 0.5f * v + va[i];
            const bool fire = (v >= 1.0f);
            __builtin_nontemporal_store(fire ? 1.0f : 0.0f,
                                        &op[(size_t)(c * U + i) * n]);
            v = fire ? 0.0f : v;
        }
        // prefetch chunk c+2
        if (c + 2 < NC) {
            #pragma unroll
            for (int i = 0; i < U; i++)
                va[i] = hp[(size_t)((c + 2) * U + i) * n];
        }
        // compute chunk c+1
        #pragma unroll
        for (int i = 0; i < U; i++) {
            v = 0.5f * v + vb[i];
            const bool fire = (v >= 1.0f);
            __builtin_nontemporal_store(fire ? 1.0f : 0.0f,
                                        &op[(size_t)((c + 1) * U + i) * n]);
            v = fire ? 0.0f : v;
        }
    }
}

extern "C" void kernel_launch(void* const* d_in, const int* in_sizes, int n_in,
                              void* d_out, int out_size, void* d_ws, size_t ws_size,
                              hipStream_t stream) {
    const float* x = (const float*)d_in[0];   // (T, B, I) fp32
    const float* W = (const float*)d_in[1];   // (H, I)    fp32
    const float* b = (const float*)d_in[2];   // (H,)      fp32
    float* out = (float*)d_out;               // (T, B, H) fp32 spikes
    float* h   = (float*)d_ws;                // (T*B, H)  fp32 scratch, 64 MB

    dim3 grid(H_DIM / BN, M_DIM / BM);        // (4, 256)
    gemm_bias_f32<<<grid, 256, 0, stream>>>(x, W, b, h);

    lif_scan<<<(B_DIM * H_DIM) / 256, 256, 0, stream>>>(h, out);
}